// Round 20
// baseline (213.863 us; speedup 1.0000x reference)
//
#include <hip/hip_runtime.h>
#include <hip/hip_bf16.h>
#include <math.h>

// Problem constants
#define B_   16
#define HID_ 1024
#define LH_  32
#define LD_  128
#define BLOCK_ 16
#define NBPS_  64
#define MAXLEN_ 1024
#define SPLIT_ 8
#define CHUNK_ (MAXLEN_ / SPLIT_)   // 128

typedef float vf4 __attribute__((ext_vector_type(4)));

// ------- fused q projection + RoPE: 512 blocks (2/CU), wave-per-row-pair ----
__global__ __launch_bounds__(256) void qproj_rope_kernel(const float* __restrict__ hs,
                                                         const float* __restrict__ w,
                                                         const int* __restrict__ pid,
                                                         const int* __restrict__ nsp,
                                                         float* __restrict__ q) {
    int t = threadIdx.x;
    int h = blockIdx.x >> 4;        // 32 heads
    int g = blockIdx.x & 15;        // 16 groups of 4 low-d's
    int j = t >> 6;                 // wave 0..3 -> d = g*4 + j
    int lane = t & 63;
    int d = g * 4 + j;              // in [0,64)
    int r0 = h * 128 + d;
    int r1 = r0 + 64;

    vf4 w0[4], w1[4];
#pragma unroll
    for (int s = 0; s < 4; ++s) {
        w0[s] = *(const vf4*)&w[(size_t)r0 * HID_ + s * 256 + lane * 4];
        w1[s] = *(const vf4*)&w[(size_t)r1 * HID_ + s * 256 + lane * 4];
    }

    __shared__ float ssum[8][16];   // [j: low | j+4: high][b]
    for (int b = 0; b < B_; ++b) {
        float p0 = 0.f, p1 = 0.f;
#pragma unroll
        for (int s = 0; s < 4; ++s) {
            vf4 a = *(const vf4*)&hs[b * 1024 + s * 256 + lane * 4];
            p0 += w0[s].x*a.x + w0[s].y*a.y + w0[s].z*a.z + w0[s].w*a.w;
            p1 += w1[s].x*a.x + w1[s].y*a.y + w1[s].z*a.z + w1[s].w*a.w;
        }
#pragma unroll
        for (int o = 1; o < 64; o <<= 1) { p0 += __shfl_xor(p0, o); p1 += __shfl_xor(p1, o); }
        if (lane == 0) { ssum[j][b] = p0; ssum[j + 4][b] = p1; }
    }
    __syncthreads();
    if (t < 64) {
        int jj = t >> 4;            // 0..3
        int b  = t & 15;
        int dd = g * 4 + jj;
        double x0 = (double)ssum[jj][b];
        double x1 = (double)ssum[jj + 4][b];
        double pos = (double)(pid[b] + nsp[0]);
        double inv_freq = 1.0 / pow(10000.0, (double)dd * (1.0 / 64.0));
        double f = pos * inv_freq;
        double cs = cos(f), sn = sin(f);
        const double scale = 0.08838834764831845;   // 1/sqrt(128)
        int base = b * 4096 + h * LD_ + dd;
        q[base]      = (float)((x0 * cs - x1 * sn) * scale);
        q[base + 64] = (float)((x1 * cs + x0 * sn) * scale);
    }
}

// ------- flash-decode attention partials (R19; SPLIT=8, h-fastest grid) -----
__global__ __launch_bounds__(256) void attn_kernel(const float* __restrict__ q,
                                                   const float* __restrict__ kc,
                                                   const float* __restrict__ vc,
                                                   const int* __restrict__ btab,
                                                   const int* __restrict__ slen,
                                                   float* __restrict__ pml,
                                                   float* __restrict__ pacc) {
    int h = blockIdx.x, c = blockIdx.y, b = blockIdx.z;   // h fastest
    int L = slen[b];
    int start = c * CHUNK_;
    if (start >= L) return;             // empty chunk: no writes (combine skips)

    int bh = b * LH_ + h;
    int pbase = bh * SPLIT_ + c;
    int t = threadIdx.x;
    int lane = t & 63, wv = t >> 6;
    int sg = lane >> 4;                 // subgroup 0..3 within wave
    int lg = lane & 15;
    int d0 = lg * 8;
    int po = wv * 4 + sg;               // position offset in [0,16); pos&15 == po
    const float* qp = q + (size_t)bh * LD_ + d0;
    vf4 qa = *(const vf4*)qp;
    vf4 qb = *(const vf4*)(qp + 4);

    int end = min(start + CHUNK_, L);

    float m = -INFINITY, l = 0.f;
    float acc[8];
#pragma unroll
    for (int k = 0; k < 8; ++k) acc[k] = 0.f;

#pragma unroll 4
    for (int pos = start + po; pos < end; pos += 16) {
        int blk = btab[b * NBPS_ + (pos >> 4)];   // lane-uniform, L1-resident
        size_t off = (((size_t)blk * LH_ + h) * BLOCK_ + po) * LD_ + d0;
        vf4 k0 = *(const vf4*)(kc + off);
        vf4 k1 = *(const vf4*)(kc + off + 4);
        vf4 v0 = *(const vf4*)(vc + off);
        vf4 v1 = *(const vf4*)(vc + off + 4);

        float dot = qa.x*k0.x + qa.y*k0.y + qa.z*k0.z + qa.w*k0.w
                  + qb.x*k1.x + qb.y*k1.y + qb.z*k1.z + qb.w*k1.w;
#pragma unroll
        for (int o = 1; o < 16; o <<= 1) dot += __shfl_xor(dot, o);

        float mn = fmaxf(m, dot);
        float r = (m >= mn) ? 1.f : __expf(m - mn);
        float p = __expf(dot - mn);
        l = l * r + p;
        acc[0] = acc[0]*r + p*v0.x;  acc[1] = acc[1]*r + p*v0.y;
        acc[2] = acc[2]*r + p*v0.z;  acc[3] = acc[3]*r + p*v0.w;
        acc[4] = acc[4]*r + p*v1.x;  acc[5] = acc[5]*r + p*v1.y;
        acc[6] = acc[6]*r + p*v1.z;  acc[7] = acc[7]*r + p*v1.w;
        m = mn;
    }

    // merge the 4 16-lane groups within the wave
#pragma unroll
    for (int o = 16; o < 64; o <<= 1) {
        float m2 = __shfl_xor(m, o), l2 = __shfl_xor(l, o);
        float a2[8];
#pragma unroll
        for (int k = 0; k < 8; ++k) a2[k] = __shfl_xor(acc[k], o);
        float mn = fmaxf(m, m2);
        float ra = (m  >= mn) ? 1.f : __expf(m  - mn);
        float rb = (m2 >= mn) ? 1.f : __expf(m2 - mn);
        l = l * ra + l2 * rb;
#pragma unroll
        for (int k = 0; k < 8; ++k) acc[k] = acc[k]*ra + a2[k]*rb;
        m = mn;
    }

    __shared__ float sm[4], sl_[4], sacc[4][128];
    if (lane < 16) {
#pragma unroll
        for (int k = 0; k < 8; ++k) sacc[wv][d0 + k] = acc[k];
        if (lane == 0) { sm[wv] = m; sl_[wv] = l; }
    }
    __syncthreads();

    if (t < 64) {
        float M = fmaxf(fmaxf(sm[0], sm[1]), fmaxf(sm[2], sm[3]));
        int d = t * 2;
        float lt = 0.f, o0 = 0.f, o1 = 0.f;
#pragma unroll
        for (int w2 = 0; w2 < 4; ++w2) {
            float mw = sm[w2];
            float e = (mw >= M) ? 1.f : __expf(mw - M);
            lt += e * sl_[w2];
            o0 += e * sacc[w2][d];
            o1 += e * sacc[w2][d + 1];
        }
        pacc[(size_t)pbase * 128 + d]     = o0;
        pacc[(size_t)pbase * 128 + d + 1] = o1;
        if (t == 0) { pml[pbase * 2] = M; pml[pbase * 2 + 1] = lt; }
    }
}

// ---------------- combine chunk partials (valid chunks only) ----------------
__global__ __launch_bounds__(64) void combine_kernel(const float* __restrict__ pml,
                                                     const float* __restrict__ pacc,
                                                     const int* __restrict__ slen,
                                                     float* __restrict__ attn) {
    int bh = blockIdx.x;
    int b = bh >> 5;
    int cmax = (slen[b] + CHUNK_ - 1) >> 7;   // ceil(L/128) >= 1
    int lane = threadIdx.x;
    float M = -INFINITY;
    for (int c = 0; c < cmax; ++c) M = fmaxf(M, pml[(bh * SPLIT_ + c) * 2]);
    int d = lane * 2;
    float lt = 0.f, o0 = 0.f, o1 = 0.f;
    for (int c = 0; c < cmax; ++c) {
        float mc = pml[(bh * SPLIT_ + c) * 2];
        float e = (mc >= M) ? 1.f : __expf(mc - M);
        lt += e * pml[(bh * SPLIT_ + c) * 2 + 1];
        o0 += e * pacc[((size_t)bh * SPLIT_ + c) * 128 + d];
        o1 += e * pacc[((size_t)bh * SPLIT_ + c) * 128 + d + 1];
    }
    float inv = 1.f / lt;
    attn[(size_t)bh * LD_ + d]     = o0 * inv;
    attn[(size_t)bh * LD_ + d + 1] = o1 * inv;
}

// ------- o projection: 512 blocks (2/CU), 2 rows per block ------------------
__global__ __launch_bounds__(256) void oproj_kernel(const float* __restrict__ attn,
                                                    const float* __restrict__ w,
                                                    float* __restrict__ out) {
    int t = threadIdx.x;
    int row0 = blockIdx.x * 2;          // 1024/2 = 512 blocks
    int lane = t & 63, wv = t >> 6;

    vf4 wr0[4], wr1[4];
#pragma unroll
    for (int s = 0; s < 4; ++s) {
        wr0[s] = *(const vf4*)&w[(size_t)row0 * 4096 + s * 1024 + t * 4];
        wr1[s] = *(const vf4*)&w[(size_t)(row0 + 1) * 4096 + s * 1024 + t * 4];
    }

    __shared__ float lds[2][4][16];     // [row][wave][b]
    for (int b = 0; b < B_; ++b) {
        float p0 = 0.f, p1 = 0.f;
#pragma unroll
        for (int s = 0; s < 4; ++s) {
            vf4 a = *(const vf4*)&attn[b * 4096 + s * 1024 + t * 4];
            p0 += wr0[s].x*a.x + wr0[s].y*a.y + wr0[s].z*a.z + wr0[s].w*a.w;
            p1 += wr1[s].x*a.x + wr1[s].y*a.y + wr1[s].z*a.z + wr1[s].w*a.w;
        }
#pragma unroll
        for (int o = 1; o < 64; o <<= 1) { p0 += __shfl_xor(p0, o); p1 += __shfl_xor(p1, o); }
        if (lane == 0) { lds[0][wv][b] = p0; lds[1][wv][b] = p1; }
    }
    __syncthreads();
    if (t < 32) {
        int r = t >> 4, b = t & 15;
        out[b * HID_ + row0 + r] =
            lds[r][0][b] + lds[r][1][b] + lds[r][2][b] + lds[r][3][b];
    }
}

extern "C" void kernel_launch(void* const* d_in, const int* in_sizes, int n_in,
                              void* d_out, int out_size, void* d_ws, size_t ws_size,
                              hipStream_t stream) {
    const float* hs   = (const float*)d_in[0];
    const float* qw   = (const float*)d_in[1];
    const float* ow   = (const float*)d_in[2];
    const float* kc   = (const float*)d_in[3];
    const float* vc   = (const float*)d_in[4];
    const int*   btab = (const int*)d_in[5];
    const int*   slen = (const int*)d_in[6];
    const int*   pid  = (const int*)d_in[7];
    const int*   nsp  = (const int*)d_in[8];
    float* out = (float*)d_out;
    float* ws  = (float*)d_ws;

    float* q_ws    = ws;             // 65536 floats
    float* attn_ws = ws + 65536;     // 65536 floats
    float* pml     = ws + 131072;    // 512*8*2   = 8192 floats
    float* pacc    = ws + 139264;    // 512*8*128 = 524288 floats (2 MB)
    // DIAGNOSTIC dead buffers (duplicate attn launches)
    float* pml2    = ws + 663552;
    float* pacc2   = ws + 671744;
    float* pml3    = ws + 1196032;
    float* pacc3   = ws + 1204224;

    qproj_rope_kernel<<<512, 256, 0, stream>>>(hs, qw, pid, nsp, q_ws);
    attn_kernel<<<dim3(LH_, SPLIT_, B_), 256, 0, stream>>>(q_ws, kc, vc, btab, slen, pml, pacc);
    // DIAGNOSTIC duplicates (outputs dead): attn = (dur - 99.0)/2
    attn_kernel<<<dim3(LH_, SPLIT_, B_), 256, 0, stream>>>(q_ws, kc, vc, btab, slen, pml2, pacc2);
    attn_kernel<<<dim3(LH_, SPLIT_, B_), 256, 0, stream>>>(q_ws, kc, vc, btab, slen, pml3, pacc3);
    combine_kernel<<<B_ * LH_, 64, 0, stream>>>(pml, pacc, slen, attn_ws);
    oproj_kernel<<<512, 256, 0, stream>>>(attn_ws, ow, out);
}

// Round 21
// 98.821 us; speedup vs baseline: 2.1641x; 2.1641x over previous
//
#include <hip/hip_runtime.h>
#include <hip/hip_bf16.h>
#include <math.h>

// Problem constants
#define B_   16
#define HID_ 1024
#define LH_  32
#define LD_  128
#define BLOCK_ 16
#define NBPS_  64
#define MAXLEN_ 1024
#define SPLIT_ 8
#define CHUNK_ (MAXLEN_ / SPLIT_)   // 128

typedef float vf4 __attribute__((ext_vector_type(4)));

__device__ __forceinline__ vf4 ntload4(const float* p) {
    return __builtin_nontemporal_load((const vf4*)p);
}

// ------- fused q projection + RoPE: 512 blocks (2/CU), wave-per-row-pair ----
__global__ __launch_bounds__(256) void qproj_rope_kernel(const float* __restrict__ hs,
                                                         const float* __restrict__ w,
                                                         const int* __restrict__ pid,
                                                         const int* __restrict__ nsp,
                                                         float* __restrict__ q) {
    int t = threadIdx.x;
    int h = blockIdx.x >> 4;        // 32 heads
    int g = blockIdx.x & 15;        // 16 groups of 4 low-d's
    int j = t >> 6;                 // wave 0..3 -> d = g*4 + j
    int lane = t & 63;
    int d = g * 4 + j;              // in [0,64)
    int r0 = h * 128 + d;
    int r1 = r0 + 64;

    vf4 w0[4], w1[4];
#pragma unroll
    for (int s = 0; s < 4; ++s) {
        w0[s] = *(const vf4*)&w[(size_t)r0 * HID_ + s * 256 + lane * 4];
        w1[s] = *(const vf4*)&w[(size_t)r1 * HID_ + s * 256 + lane * 4];
    }

    __shared__ float ssum[8][16];   // [j: low | j+4: high][b]
    for (int b = 0; b < B_; ++b) {
        float p0 = 0.f, p1 = 0.f;
#pragma unroll
        for (int s = 0; s < 4; ++s) {
            vf4 a = *(const vf4*)&hs[b * 1024 + s * 256 + lane * 4];
            p0 += w0[s].x*a.x + w0[s].y*a.y + w0[s].z*a.z + w0[s].w*a.w;
            p1 += w1[s].x*a.x + w1[s].y*a.y + w1[s].z*a.z + w1[s].w*a.w;
        }
#pragma unroll
        for (int o = 1; o < 64; o <<= 1) { p0 += __shfl_xor(p0, o); p1 += __shfl_xor(p1, o); }
        if (lane == 0) { ssum[j][b] = p0; ssum[j + 4][b] = p1; }
    }
    __syncthreads();
    if (t < 64) {
        int jj = t >> 4;            // 0..3
        int b  = t & 15;
        int dd = g * 4 + jj;
        double x0 = (double)ssum[jj][b];
        double x1 = (double)ssum[jj + 4][b];
        double pos = (double)(pid[b] + nsp[0]);
        double inv_freq = 1.0 / pow(10000.0, (double)dd * (1.0 / 64.0));
        double f = pos * inv_freq;
        double cs = cos(f), sn = sin(f);
        const double scale = 0.08838834764831845;   // 1/sqrt(128)
        int base = b * 4096 + h * LD_ + dd;
        q[base]      = (float)((x0 * cs - x1 * sn) * scale);
        q[base + 64] = (float)((x1 * cs + x0 * sn) * scale);
    }
}

// ------- flash-decode attention partials (R19 + nontemporal K/V loads) ------
// KV stream has zero reuse -> nt loads bypass cache-fill; single variable vs R19.
__global__ __launch_bounds__(256) void attn_kernel(const float* __restrict__ q,
                                                   const float* __restrict__ kc,
                                                   const float* __restrict__ vc,
                                                   const int* __restrict__ btab,
                                                   const int* __restrict__ slen,
                                                   float* __restrict__ pml,
                                                   float* __restrict__ pacc) {
    int h = blockIdx.x, c = blockIdx.y, b = blockIdx.z;   // h fastest
    int L = slen[b];
    int start = c * CHUNK_;
    if (start >= L) return;             // empty chunk: no writes (combine skips)

    int bh = b * LH_ + h;
    int pbase = bh * SPLIT_ + c;
    int t = threadIdx.x;
    int lane = t & 63, wv = t >> 6;
    int sg = lane >> 4;                 // subgroup 0..3 within wave
    int lg = lane & 15;
    int d0 = lg * 8;
    int po = wv * 4 + sg;               // position offset in [0,16); pos&15 == po
    const float* qp = q + (size_t)bh * LD_ + d0;
    vf4 qa = *(const vf4*)qp;
    vf4 qb = *(const vf4*)(qp + 4);

    int end = min(start + CHUNK_, L);

    float m = -INFINITY, l = 0.f;
    float acc[8];
#pragma unroll
    for (int k = 0; k < 8; ++k) acc[k] = 0.f;

#pragma unroll 4
    for (int pos = start + po; pos < end; pos += 16) {
        int blk = btab[b * NBPS_ + (pos >> 4)];   // lane-uniform, L1-resident
        size_t off = (((size_t)blk * LH_ + h) * BLOCK_ + po) * LD_ + d0;
        vf4 k0 = ntload4(kc + off);
        vf4 k1 = ntload4(kc + off + 4);
        vf4 v0 = ntload4(vc + off);
        vf4 v1 = ntload4(vc + off + 4);

        float dot = qa.x*k0.x + qa.y*k0.y + qa.z*k0.z + qa.w*k0.w
                  + qb.x*k1.x + qb.y*k1.y + qb.z*k1.z + qb.w*k1.w;
#pragma unroll
        for (int o = 1; o < 16; o <<= 1) dot += __shfl_xor(dot, o);

        float mn = fmaxf(m, dot);
        float r = (m >= mn) ? 1.f : __expf(m - mn);
        float p = __expf(dot - mn);
        l = l * r + p;
        acc[0] = acc[0]*r + p*v0.x;  acc[1] = acc[1]*r + p*v0.y;
        acc[2] = acc[2]*r + p*v0.z;  acc[3] = acc[3]*r + p*v0.w;
        acc[4] = acc[4]*r + p*v1.x;  acc[5] = acc[5]*r + p*v1.y;
        acc[6] = acc[6]*r + p*v1.z;  acc[7] = acc[7]*r + p*v1.w;
        m = mn;
    }

    // merge the 4 16-lane groups within the wave
#pragma unroll
    for (int o = 16; o < 64; o <<= 1) {
        float m2 = __shfl_xor(m, o), l2 = __shfl_xor(l, o);
        float a2[8];
#pragma unroll
        for (int k = 0; k < 8; ++k) a2[k] = __shfl_xor(acc[k], o);
        float mn = fmaxf(m, m2);
        float ra = (m  >= mn) ? 1.f : __expf(m  - mn);
        float rb = (m2 >= mn) ? 1.f : __expf(m2 - mn);
        l = l * ra + l2 * rb;
#pragma unroll
        for (int k = 0; k < 8; ++k) acc[k] = acc[k]*ra + a2[k]*rb;
        m = mn;
    }

    __shared__ float sm[4], sl_[4], sacc[4][128];
    if (lane < 16) {
#pragma unroll
        for (int k = 0; k < 8; ++k) sacc[wv][d0 + k] = acc[k];
        if (lane == 0) { sm[wv] = m; sl_[wv] = l; }
    }
    __syncthreads();

    if (t < 64) {
        float M = fmaxf(fmaxf(sm[0], sm[1]), fmaxf(sm[2], sm[3]));
        int d = t * 2;
        float lt = 0.f, o0 = 0.f, o1 = 0.f;
#pragma unroll
        for (int w2 = 0; w2 < 4; ++w2) {
            float mw = sm[w2];
            float e = (mw >= M) ? 1.f : __expf(mw - M);
            lt += e * sl_[w2];
            o0 += e * sacc[w2][d];
            o1 += e * sacc[w2][d + 1];
        }
        pacc[(size_t)pbase * 128 + d]     = o0;
        pacc[(size_t)pbase * 128 + d + 1] = o1;
        if (t == 0) { pml[pbase * 2] = M; pml[pbase * 2 + 1] = lt; }
    }
}

// ---------------- combine chunk partials (valid chunks only) ----------------
__global__ __launch_bounds__(64) void combine_kernel(const float* __restrict__ pml,
                                                     const float* __restrict__ pacc,
                                                     const int* __restrict__ slen,
                                                     float* __restrict__ attn) {
    int bh = blockIdx.x;
    int b = bh >> 5;
    int cmax = (slen[b] + CHUNK_ - 1) >> 7;   // ceil(L/128) >= 1
    int lane = threadIdx.x;
    float M = -INFINITY;
    for (int c = 0; c < cmax; ++c) M = fmaxf(M, pml[(bh * SPLIT_ + c) * 2]);
    int d = lane * 2;
    float lt = 0.f, o0 = 0.f, o1 = 0.f;
    for (int c = 0; c < cmax; ++c) {
        float mc = pml[(bh * SPLIT_ + c) * 2];
        float e = (mc >= M) ? 1.f : __expf(mc - M);
        lt += e * pml[(bh * SPLIT_ + c) * 2 + 1];
        o0 += e * pacc[((size_t)bh * SPLIT_ + c) * 128 + d];
        o1 += e * pacc[((size_t)bh * SPLIT_ + c) * 128 + d + 1];
    }
    float inv = 1.f / lt;
    attn[(size_t)bh * LD_ + d]     = o0 * inv;
    attn[(size_t)bh * LD_ + d + 1] = o1 * inv;
}

// ------- o projection: 512 blocks (2/CU), 2 rows per block ------------------
__global__ __launch_bounds__(256) void oproj_kernel(const float* __restrict__ attn,
                                                    const float* __restrict__ w,
                                                    float* __restrict__ out) {
    int t = threadIdx.x;
    int row0 = blockIdx.x * 2;          // 1024/2 = 512 blocks
    int lane = t & 63, wv = t >> 6;

    vf4 wr0[4], wr1[4];
#pragma unroll
    for (int s = 0; s < 4; ++s) {
        wr0[s] = *(const vf4*)&w[(size_t)row0 * 4096 + s * 1024 + t * 4];
        wr1[s] = *(const vf4*)&w[(size_t)(row0 + 1) * 4096 + s * 1024 + t * 4];
    }

    __shared__ float lds[2][4][16];     // [row][wave][b]
    for (int b = 0; b < B_; ++b) {
        float p0 = 0.f, p1 = 0.f;
#pragma unroll
        for (int s = 0; s < 4; ++s) {
            vf4 a = *(const vf4*)&attn[b * 4096 + s * 1024 + t * 4];
            p0 += wr0[s].x*a.x + wr0[s].y*a.y + wr0[s].z*a.z + wr0[s].w*a.w;
            p1 += wr1[s].x*a.x + wr1[s].y*a.y + wr1[s].z*a.z + wr1[s].w*a.w;
        }
#pragma unroll
        for (int o = 1; o < 64; o <<= 1) { p0 += __shfl_xor(p0, o); p1 += __shfl_xor(p1, o); }
        if (lane == 0) { lds[0][wv][b] = p0; lds[1][wv][b] = p1; }
    }
    __syncthreads();
    if (t < 32) {
        int r = t >> 4, b = t & 15;
        out[b * HID_ + row0 + r] =
            lds[r][0][b] + lds[r][1][b] + lds[r][2][b] + lds[r][3][b];
    }
}

extern "C" void kernel_launch(void* const* d_in, const int* in_sizes, int n_in,
                              void* d_out, int out_size, void* d_ws, size_t ws_size,
                              hipStream_t stream) {
    const float* hs   = (const float*)d_in[0];
    const float* qw   = (const float*)d_in[1];
    const float* ow   = (const float*)d_in[2];
    const float* kc   = (const float*)d_in[3];
    const float* vc   = (const float*)d_in[4];
    const int*   btab = (const int*)d_in[5];
    const int*   slen = (const int*)d_in[6];
    const int*   pid  = (const int*)d_in[7];
    const int*   nsp  = (const int*)d_in[8];
    float* out = (float*)d_out;
    float* ws  = (float*)d_ws;

    float* q_ws    = ws;             // 65536 floats
    float* attn_ws = ws + 65536;     // 65536 floats
    float* pml     = ws + 131072;    // 512*8*2   = 8192 floats
    float* pacc    = ws + 139264;    // 512*8*128 = 524288 floats (2 MB)

    qproj_rope_kernel<<<512, 256, 0, stream>>>(hs, qw, pid, nsp, q_ws);
    attn_kernel<<<dim3(LH_, SPLIT_, B_), 256, 0, stream>>>(q_ws, kc, vc, btab, slen, pml, pacc);
    combine_kernel<<<B_ * LH_, 64, 0, stream>>>(pml, pacc, slen, attn_ws);
    oproj_kernel<<<512, 256, 0, stream>>>(attn_ws, ow, out);
}